// Round 7
// baseline (137.048 us; speedup 1.0000x reference)
//
#include <hip/hip_runtime.h>
#include <hip/hip_fp16.h>

#define D 128
#define TWO_D 256

typedef _Float16 half2v __attribute__((ext_vector_type(2)));
typedef _Float16 half8v __attribute__((ext_vector_type(8)));
typedef float floatx4 __attribute__((ext_vector_type(4)));
typedef unsigned int uintx4 __attribute__((ext_vector_type(4)));

__device__ inline unsigned int pkrtz(float a, float b) {
    return __builtin_bit_cast(unsigned int, __builtin_amdgcn_cvt_pkrtz(a, b));
}

// v10 gemm: build_wtf is FUSED — each block constructs its B-fragments
// directly from W1 (L2-hot broadcast; per (t,ks) the wave reads 16 full
// 128 B lines, fully consumed). x staging loads are issued FIRST so their
// ~900 cy HBM latency hides under fragment construction. AB keeps the
// v9 fragment-permuted layout: byte p of each 128 B half holds col
// o = (p>>6)*64 + (p&3)*16 + ((p&63)>>2), so each lane stores its 4
// accumulator values as one dword (no LDS repack, 1 barrier total).
__global__ __launch_bounds__(256) void gemm_nodes(
        const float* __restrict__ x, const float* __restrict__ W1,
        const float* __restrict__ b1,
        unsigned char* __restrict__ AB, float* __restrict__ out0, int nNodes) {
    const int tid  = threadIdx.x;
    const int wave = tid >> 6, lane = tid & 63;
    const int quad = lane >> 4, l16 = lane & 15;
    const int nb0  = blockIdx.x * 64;

    if (blockIdx.x == 0 && tid == 0) *out0 = 0.f;   // replaces hipMemsetAsync

    // Phase 0: issue all 8 x-row loads (HBM) into regs, back-to-back.
    floatx4 xv[4][2];
#pragma unroll
    for (int i = 0; i < 4; ++i) {
        const int c = tid + 256 * i;          // 0..1023
        const int row = c >> 4, col8 = c & 15;
        const int node = nb0 + row;
        const int nc = node < nNodes ? node : nNodes - 1;
        const float* xp = x + (size_t)nc * D + col8 * 8;
        xv[i][0] = *(const floatx4*)xp;
        xv[i][1] = *(const floatx4*)(xp + 4);
    }

    // Phase 1: B-fragments straight from W1 (L2-hot; overlaps x latency).
    // Bf[t][ks] elem j = fp16(W1eff[o][32ks+8quad+j]), o = wave*64+16t+l16.
    half8v Bf[4][4];
    float bias[4];
#pragma unroll
    for (int t = 0; t < 4; ++t) {
        const int o = wave * 64 + t * 16 + l16;
        bias[t] = (o < D) ? b1[o] : 0.f;
        const float* wrow = (o < D) ? (W1 + (size_t)o * TWO_D)
                                    : (W1 + (size_t)(o - D) * TWO_D + D);
#pragma unroll
        for (int ks = 0; ks < 4; ++ks) {
            const float* wp = wrow + ks * 32 + quad * 8;
            floatx4 w0 = *(const floatx4*)wp;
            floatx4 w1v = *(const floatx4*)(wp + 4);
            uint4 pk;
            pk.x = pkrtz(w0[0], w0[1]);   pk.y = pkrtz(w0[2], w0[3]);
            pk.z = pkrtz(w1v[0], w1v[1]); pk.w = pkrtz(w1v[2], w1v[3]);
            Bf[t][ks] = __builtin_bit_cast(half8v, pk);
        }
    }

    __shared__ __align__(16) unsigned short xs[64][136];   // 64 rows, 17.4 KB

    // Phase 2: convert staged x rows to fp16 in LDS.
#pragma unroll
    for (int i = 0; i < 4; ++i) {
        const int c = tid + 256 * i;
        const int row = c >> 4, col8 = c & 15;
        uint4 pk;
        pk.x = pkrtz(xv[i][0][0], xv[i][0][1]);
        pk.y = pkrtz(xv[i][0][2], xv[i][0][3]);
        pk.z = pkrtz(xv[i][1][0], xv[i][1][1]);
        pk.w = pkrtz(xv[i][1][2], xv[i][1][3]);
        *(uint4*)&xs[row][col8 * 8] = pk;
    }
    __syncthreads();   // sole barrier

    for (int sub = 0; sub < 4; ++sub) {
        // A-frags: m = lane&15 (node within sub-tile), k = quad*8 + j + 32*ks
        half8v Af[4];
#pragma unroll
        for (int ks = 0; ks < 4; ++ks)
            Af[ks] = *(const half8v*)&xs[sub * 16 + l16][ks * 32 + quad * 8];

        floatx4 acc[4];
#pragma unroll
        for (int t = 0; t < 4; ++t) acc[t] = (floatx4){0.f, 0.f, 0.f, 0.f};
#pragma unroll
        for (int ks = 0; ks < 4; ++ks)
#pragma unroll
            for (int t = 0; t < 4; ++t)
                acc[t] = __builtin_amdgcn_mfma_f32_16x16x32_f16(Af[ks], Bf[t][ks], acc[t], 0, 0, 0);

        // Direct fragment-order store: lane holds rows quad*4+r, cols
        // o = wave*64 + t*16 + l16 -> dword [t0..t3] at byte wave*64+l16*4.
#pragma unroll
        for (int r = 0; r < 4; ++r) {
            const int nrow = nb0 + sub * 16 + quad * 4 + r;
            if (nrow < nNodes) {
                int d;
                d = __builtin_amdgcn_cvt_pk_fp8_f32(acc[0][r] + bias[0],
                                                    acc[1][r] + bias[1], 0, false);
                d = __builtin_amdgcn_cvt_pk_fp8_f32(acc[2][r] + bias[2],
                                                    acc[3][r] + bias[3], d, true);
                *(unsigned int*)(AB + (size_t)nrow * TWO_D + wave * 64 + l16 * 4) =
                    (unsigned int)d;
            }
        }
    }
}

// relu(a+b) dot w2 for 4 fp8 elements packed in dwords wa/wb; w2 as 2 f16-pairs.
__device__ inline float dot4_fp8(unsigned int wa, unsigned int wb,
                                 unsigned int w2lo, unsigned int w2hi, float z) {
#if __has_builtin(__builtin_amdgcn_cvt_pk_f16_fp8)
    half2v a01 = __builtin_bit_cast(half2v, __builtin_amdgcn_cvt_pk_f16_fp8((short)(wa & 0xffffu)));
    half2v a23 = __builtin_bit_cast(half2v, __builtin_amdgcn_cvt_pk_f16_fp8((short)(wa >> 16)));
    half2v b01 = __builtin_bit_cast(half2v, __builtin_amdgcn_cvt_pk_f16_fp8((short)(wb & 0xffffu)));
    half2v b23 = __builtin_bit_cast(half2v, __builtin_amdgcn_cvt_pk_f16_fp8((short)(wb >> 16)));
    half2v zero = {(_Float16)0, (_Float16)0};
    half2v s01 = __builtin_elementwise_max(a01 + b01, zero);
    half2v s23 = __builtin_elementwise_max(a23 + b23, zero);
    z = __builtin_amdgcn_fdot2(s01, __builtin_bit_cast(half2v, w2lo), z, false);
    z = __builtin_amdgcn_fdot2(s23, __builtin_bit_cast(half2v, w2hi), z, false);
#else
    auto a01 = __builtin_amdgcn_cvt_pk_f32_fp8(wa, false);
    auto a23 = __builtin_amdgcn_cvt_pk_f32_fp8(wa, true);
    auto b01 = __builtin_amdgcn_cvt_pk_f32_fp8(wb, false);
    auto b23 = __builtin_amdgcn_cvt_pk_f32_fp8(wb, true);
    half2v wlo = __builtin_bit_cast(half2v, w2lo);
    half2v whi = __builtin_bit_cast(half2v, w2hi);
    float s0 = fmaxf(a01[0] + b01[0], 0.f), s1 = fmaxf(a01[1] + b01[1], 0.f);
    float s2 = fmaxf(a23[0] + b23[0], 0.f), s3 = fmaxf(a23[1] + b23[1], 0.f);
    z = fmaf(s0, (float)wlo[0], z); z = fmaf(s1, (float)wlo[1], z);
    z = fmaf(s2, (float)whi[0], z); z = fmaf(s3, (float)whi[1], z);
#endif
    return z;
}

__device__ inline float dot16(const uintx4 a4, const uintx4 b4,
                              const uintx4 w2a, const uintx4 w2b) {
    float z = 0.f;
    z = dot4_fp8(a4[0], b4[0], w2a[0], w2a[1], z);
    z = dot4_fp8(a4[1], b4[1], w2a[2], w2a[3], z);
    z = dot4_fp8(a4[2], b4[2], w2b[0], w2b[1], z);
    z = dot4_fp8(a4[3], b4[3], w2b[2], w2b[3], z);
    return z;
}

__device__ inline float red8(float z) {
    z += __shfl_xor(z, 4, 8);
    z += __shfl_xor(z, 2, 8);
    z += __shfl_xor(z, 1, 8);
    return z;
}

__device__ inline float bce(float z, float y) {
    const float t = __expf(-fabsf(z));
    return fmaxf(z, 0.f) - z * y + __logf(1.f + t);
}

// edge_loss: byte-identical to R5 (proven best, ~43 us at the measured
// ~28 G random-lines/s service wall). w2p built with the AB fragment
// permutation j(b) = (b>>6)*64 + (b&3)*16 + ((b&63)>>2).
__global__ __launch_bounds__(256) void edge_loss(
        const unsigned char* __restrict__ AB,
        const int* __restrict__ pairs,
        const float* __restrict__ labels,
        const float* __restrict__ W2,
        const float* __restrict__ b2,
        float* __restrict__ out, int E, float invE) {
    __shared__ unsigned int w2p[64];   // permuted W2 as 64 packed f16 pairs
    const int tid = threadIdx.x;
    if (tid < 64) {
        const int b0 = 2 * tid, b1 = 2 * tid + 1;
        const int j0 = (b0 >> 6) * 64 + (b0 & 3) * 16 + ((b0 & 63) >> 2);
        const int j1 = (b1 >> 6) * 64 + (b1 & 3) * 16 + ((b1 & 63) >> 2);
        half2v p = { (_Float16)W2[j0], (_Float16)W2[j1] };
        w2p[tid] = __builtin_bit_cast(unsigned int, p);
    }
    __syncthreads();
    const int l8   = tid & 7;
    const uintx4 w2a = *(const uintx4*)&w2p[l8 * 8];     // pairs for bytes [16l8, +8)
    const uintx4 w2b = *(const uintx4*)&w2p[l8 * 8 + 4]; // pairs for bytes [16l8+8, +8)
    const float bb2 = b2[0];

    float acc = 0.f;
    const int group = (blockIdx.x * 256 + tid) >> 3;     // one 8-edge chunk per group
    const int e0 = group * 8;
    if (e0 < E) {                                        // E % 8 == 0: full chunks
        // Group-wide index spans (broadcast within group, coalesced across wave).
        const int4 ua = *(const int4*)(pairs + e0);
        const int4 ub = *(const int4*)(pairs + e0 + 4);
        const int4 va = *(const int4*)(pairs + E + e0);
        const int4 vb = *(const int4*)(pairs + E + e0 + 4);
        const float lab = labels[e0 + l8];               // coalesced, per-lane edge
        const int us[8] = {ua.x, ua.y, ua.z, ua.w, ub.x, ub.y, ub.z, ub.w};
        const int vs[8] = {va.x, va.y, va.z, va.w, vb.x, vb.y, vb.z, vb.w};

        // 32-bit offsets (AB is 12.8 MB): SGPR-base + voffset form, 1 VGPR/addr.
        unsigned int offA[8], offB[8];
#pragma unroll
        for (int k = 0; k < 8; ++k) {
            offA[k] = (unsigned int)us[k] * TWO_D + l8 * 16;
            offB[k] = (unsigned int)vs[k] * TWO_D + D + l8 * 16;
        }

        uintx4 A[8], B[8];
#pragma unroll
        for (int k = 0; k < 8; ++k) {    // 16 loads issued back-to-back, pinned
            asm volatile("global_load_dwordx4 %0, %1, %2"
                         : "=v"(A[k]) : "v"(offA[k]), "s"(AB) : "memory");
            asm volatile("global_load_dwordx4 %0, %1, %2"
                         : "=v"(B[k]) : "v"(offB[k]), "s"(AB) : "memory");
        }

        float z[8];
#define CONS2(k0, k1, cnt)                                                   \
        asm volatile("s_waitcnt vmcnt(" cnt ")" ::: "memory");               \
        __builtin_amdgcn_sched_barrier(0);                                   \
        z[k0] = red8(dot16(A[k0], B[k0], w2a, w2b));                         \
        z[k1] = red8(dot16(A[k1], B[k1], w2a, w2b));
        CONS2(0, 1, "12")
        CONS2(2, 3, "8")
        CONS2(4, 5, "4")
        CONS2(6, 7, "0")
#undef CONS2

        // lane k of the group owns edge k (z is an all-reduce result)
        float zsel = z[0];
#pragma unroll
        for (int k = 1; k < 8; ++k)
            if (l8 == k) zsel = z[k];
        acc = bce(zsel + bb2, lab);
    }

    // wave butterfly -> LDS -> one atomic per block
#pragma unroll
    for (int m = 32; m >= 1; m >>= 1) acc += __shfl_xor(acc, m, 64);
    __shared__ float red[4];
    if ((tid & 63) == 0) red[tid >> 6] = acc;
    __syncthreads();
    if (tid == 0)
        atomicAdd(out, (red[0] + red[1] + red[2] + red[3]) * invE);
}

extern "C" void kernel_launch(void* const* d_in, const int* in_sizes, int n_in,
                              void* d_out, int out_size, void* d_ws, size_t ws_size,
                              hipStream_t stream) {
    const float* x      = (const float*)d_in[0];
    const float* W1     = (const float*)d_in[1];
    const float* b1     = (const float*)d_in[2];
    const float* W2     = (const float*)d_in[3];
    const float* b2     = (const float*)d_in[4];
    const float* labels = (const float*)d_in[5];
    const int*   pairs  = (const int*)d_in[6];

    const int nNodes = in_sizes[0] / D;   // 50000
    const int E      = in_sizes[5];       // 600000

    unsigned char* AB = (unsigned char*)d_ws;   // 12.8 MB fp8, fragment-permuted

    gemm_nodes<<<(nNodes + 63) / 64, 256, 0, stream>>>(x, W1, b1, AB,
                                                        (float*)d_out, nNodes);
    const int nGroups = (E + 7) / 8;                    // 75000
    const int nBlocks = (nGroups + 31) / 32;            // 2344 (32 groups/block)
    edge_loss<<<nBlocks, 256, 0, stream>>>(AB, pairs, labels, W2, b2,
                                           (float*)d_out, E, 1.0f / (float)E);
}

// Round 8
// 126.981 us; speedup vs baseline: 1.0793x; 1.0793x over previous
//
#include <hip/hip_runtime.h>
#include <hip/hip_fp16.h>

#define D 128
#define TWO_D 256

typedef _Float16 half2v __attribute__((ext_vector_type(2)));
typedef _Float16 half8v __attribute__((ext_vector_type(8)));
typedef float floatx4 __attribute__((ext_vector_type(4)));
typedef unsigned int uintx4 __attribute__((ext_vector_type(4)));

__device__ inline unsigned int pkrtz(float a, float b) {
    return __builtin_bit_cast(unsigned int, __builtin_amdgcn_cvt_pkrtz(a, b));
}

// Build Wt in MFMA B-fragment order so gemm's prologue loads are coalesced.
// Fragment element (w,t,ks,lane) = W1eff[o][k], o = 64w+16t+(lane&15),
// k = 32ks + 8*(lane>>4) + j, j=0..7 (8 fp16 = 16 B per lane).
// (restored from R5: the fused variant cost ~9 us in gemm — reverted)
__global__ void build_wtf(const float* __restrict__ W1,
                          unsigned short* __restrict__ Wtf) {
    const int id = blockIdx.x * 256 + threadIdx.x;   // 4096 total
    const int lane = id & 63, ks = (id >> 6) & 3, t = (id >> 8) & 3, w = id >> 10;
    const int quad = lane >> 4, l16 = lane & 15;
    const int o = w * 64 + t * 16 + l16;
    const float* wrow = (o < D) ? (W1 + (size_t)o * TWO_D)
                                : (W1 + (size_t)(o - D) * TWO_D + D);
    const float* wp = wrow + ks * 32 + quad * 8;
    floatx4 w0 = *(const floatx4*)wp;
    floatx4 w1v = *(const floatx4*)(wp + 4);
    uint4 pk;
    pk.x = pkrtz(w0[0], w0[1]);  pk.y = pkrtz(w0[2], w0[3]);
    pk.z = pkrtz(w1v[0], w1v[1]); pk.w = pkrtz(w1v[2], w1v[3]);
    *(uint4*)(Wtf + (size_t)id * 8) = pk;
}

// v9 gemm (byte-identical to R5): AB stored in FRAGMENT-PERMUTED layout —
// byte p of each 128 B half holds col o = (p>>6)*64 + (p&3)*16 + ((p&63)>>2).
// Each lane packs its 4 MFMA accumulator values into ONE dword and stores
// directly: no ct LDS repack, 1 barrier total, LDS 17.4 KB.
__global__ __launch_bounds__(256) void gemm_nodes(
        const float* __restrict__ x, const unsigned short* __restrict__ Wtf,
        const float* __restrict__ b1,
        unsigned char* __restrict__ AB, float* __restrict__ out0, int nNodes) {
    const int tid  = threadIdx.x;
    const int wave = tid >> 6, lane = tid & 63;
    const int quad = lane >> 4, l16 = lane & 15;
    const int nb0  = blockIdx.x * 64;

    if (blockIdx.x == 0 && tid == 0) *out0 = 0.f;   // replaces hipMemsetAsync

    // B-operand frags: coalesced 16 B/lane loads from fragment-ordered Wtf.
    half8v Bf[4][4];
    float bias[4];
#pragma unroll
    for (int t = 0; t < 4; ++t) {
        const int o = wave * 64 + t * 16 + l16;
        bias[t] = (o < D) ? b1[o] : 0.f;
#pragma unroll
        for (int ks = 0; ks < 4; ++ks)
            Bf[t][ks] = *(const half8v*)(Wtf +
                ((size_t)(((wave * 4 + t) * 4 + ks) * 64) + lane) * 8);
    }

    __shared__ __align__(16) unsigned short xs[64][136];   // 64 rows, 17.4 KB

    // Phase 1: stage all 64 node-rows fp16 (1024 8-float chunks / 256 threads).
#pragma unroll
    for (int i = 0; i < 4; ++i) {
        const int c = tid + 256 * i;          // 0..1023
        const int row = c >> 4, col8 = c & 15;
        const int node = nb0 + row;
        const int nc = node < nNodes ? node : nNodes - 1;
        const float* xp = x + (size_t)nc * D + col8 * 8;
        floatx4 v0 = *(const floatx4*)xp;
        floatx4 v1 = *(const floatx4*)(xp + 4);
        uint4 pk;
        pk.x = pkrtz(v0[0], v0[1]);  pk.y = pkrtz(v0[2], v0[3]);
        pk.z = pkrtz(v1[0], v1[1]);  pk.w = pkrtz(v1[2], v1[3]);
        *(uint4*)&xs[row][col8 * 8] = pk;
    }
    __syncthreads();   // sole barrier

    for (int sub = 0; sub < 4; ++sub) {
        // A-frags: m = lane&15 (node within sub-tile), k = quad*8 + j + 32*ks
        half8v Af[4];
#pragma unroll
        for (int ks = 0; ks < 4; ++ks)
            Af[ks] = *(const half8v*)&xs[sub * 16 + l16][ks * 32 + quad * 8];

        floatx4 acc[4];
#pragma unroll
        for (int t = 0; t < 4; ++t) acc[t] = (floatx4){0.f, 0.f, 0.f, 0.f};
#pragma unroll
        for (int ks = 0; ks < 4; ++ks)
#pragma unroll
            for (int t = 0; t < 4; ++t)
                acc[t] = __builtin_amdgcn_mfma_f32_16x16x32_f16(Af[ks], Bf[t][ks], acc[t], 0, 0, 0);

        // Direct fragment-order store: lane holds rows quad*4+r, cols
        // o = wave*64 + t*16 + l16 -> dword [t0..t3] at byte wave*64+l16*4.
#pragma unroll
        for (int r = 0; r < 4; ++r) {
            const int nrow = nb0 + sub * 16 + quad * 4 + r;
            if (nrow < nNodes) {
                int d;
                d = __builtin_amdgcn_cvt_pk_fp8_f32(acc[0][r] + bias[0],
                                                    acc[1][r] + bias[1], 0, false);
                d = __builtin_amdgcn_cvt_pk_fp8_f32(acc[2][r] + bias[2],
                                                    acc[3][r] + bias[3], d, true);
                *(unsigned int*)(AB + (size_t)nrow * TWO_D + wave * 64 + l16 * 4) =
                    (unsigned int)d;
            }
        }
    }
}

// relu(a+b) dot w2 for 4 fp8 elements packed in dwords wa/wb; w2 as 2 f16-pairs.
__device__ inline float dot4_fp8(unsigned int wa, unsigned int wb,
                                 unsigned int w2lo, unsigned int w2hi, float z) {
#if __has_builtin(__builtin_amdgcn_cvt_pk_f16_fp8)
    half2v a01 = __builtin_bit_cast(half2v, __builtin_amdgcn_cvt_pk_f16_fp8((short)(wa & 0xffffu)));
    half2v a23 = __builtin_bit_cast(half2v, __builtin_amdgcn_cvt_pk_f16_fp8((short)(wa >> 16)));
    half2v b01 = __builtin_bit_cast(half2v, __builtin_amdgcn_cvt_pk_f16_fp8((short)(wb & 0xffffu)));
    half2v b23 = __builtin_bit_cast(half2v, __builtin_amdgcn_cvt_pk_f16_fp8((short)(wb >> 16)));
    half2v zero = {(_Float16)0, (_Float16)0};
    half2v s01 = __builtin_elementwise_max(a01 + b01, zero);
    half2v s23 = __builtin_elementwise_max(a23 + b23, zero);
    z = __builtin_amdgcn_fdot2(s01, __builtin_bit_cast(half2v, w2lo), z, false);
    z = __builtin_amdgcn_fdot2(s23, __builtin_bit_cast(half2v, w2hi), z, false);
#else
    auto a01 = __builtin_amdgcn_cvt_pk_f32_fp8(wa, false);
    auto a23 = __builtin_amdgcn_cvt_pk_f32_fp8(wa, true);
    auto b01 = __builtin_amdgcn_cvt_pk_f32_fp8(wb, false);
    auto b23 = __builtin_amdgcn_cvt_pk_f32_fp8(wb, true);
    half2v wlo = __builtin_bit_cast(half2v, w2lo);
    half2v whi = __builtin_bit_cast(half2v, w2hi);
    float s0 = fmaxf(a01[0] + b01[0], 0.f), s1 = fmaxf(a01[1] + b01[1], 0.f);
    float s2 = fmaxf(a23[0] + b23[0], 0.f), s3 = fmaxf(a23[1] + b23[1], 0.f);
    z = fmaf(s0, (float)wlo[0], z); z = fmaf(s1, (float)wlo[1], z);
    z = fmaf(s2, (float)whi[0], z); z = fmaf(s3, (float)whi[1], z);
#endif
    return z;
}

__device__ inline float dot16(const uintx4 a4, const uintx4 b4,
                              const uintx4 w2a, const uintx4 w2b) {
    float z = 0.f;
    z = dot4_fp8(a4[0], b4[0], w2a[0], w2a[1], z);
    z = dot4_fp8(a4[1], b4[1], w2a[2], w2a[3], z);
    z = dot4_fp8(a4[2], b4[2], w2b[0], w2b[1], z);
    z = dot4_fp8(a4[3], b4[3], w2b[2], w2b[3], z);
    return z;
}

__device__ inline float red8(float z) {
    z += __shfl_xor(z, 4, 8);
    z += __shfl_xor(z, 2, 8);
    z += __shfl_xor(z, 1, 8);
    return z;
}

__device__ inline float bce(float z, float y) {
    const float t = __expf(-fabsf(z));
    return fmaxf(z, 0.f) - z * y + __logf(1.f + t);
}

// edge_loss: R5 source + __launch_bounds__(256, 4).
// R7 exposed a codegen pathology: with the default bounds the allocator
// squeezed this kernel to 44 VGPRs — below the 64 needed to keep 16
// dwordx4 gathers in flight — serializing the pipeline (48.2 us vs ~43 in
// the R2-R5 builds, byte-identical source, different co-compilation
// context; rule #19). min-waves/EU=4 sets the VGPR budget to 128/lane so
// the 16-deep pipeline allocation is stable regardless of context.
// 4 waves/EU = 16 waves/CU ~= the 30-35% occupancy it runs at anyway.
__global__ __launch_bounds__(256, 4) void edge_loss(
        const unsigned char* __restrict__ AB,
        const int* __restrict__ pairs,
        const float* __restrict__ labels,
        const float* __restrict__ W2,
        const float* __restrict__ b2,
        float* __restrict__ out, int E, float invE) {
    __shared__ unsigned int w2p[64];   // permuted W2 as 64 packed f16 pairs
    const int tid = threadIdx.x;
    if (tid < 64) {
        const int b0 = 2 * tid, b1 = 2 * tid + 1;
        const int j0 = (b0 >> 6) * 64 + (b0 & 3) * 16 + ((b0 & 63) >> 2);
        const int j1 = (b1 >> 6) * 64 + (b1 & 3) * 16 + ((b1 & 63) >> 2);
        half2v p = { (_Float16)W2[j0], (_Float16)W2[j1] };
        w2p[tid] = __builtin_bit_cast(unsigned int, p);
    }
    __syncthreads();
    const int l8   = tid & 7;
    const uintx4 w2a = *(const uintx4*)&w2p[l8 * 8];     // pairs for bytes [16l8, +8)
    const uintx4 w2b = *(const uintx4*)&w2p[l8 * 8 + 4]; // pairs for bytes [16l8+8, +8)
    const float bb2 = b2[0];

    float acc = 0.f;
    const int group = (blockIdx.x * 256 + tid) >> 3;     // one 8-edge chunk per group
    const int e0 = group * 8;
    if (e0 < E) {                                        // E % 8 == 0: full chunks
        // Group-wide index spans (broadcast within group, coalesced across wave).
        const int4 ua = *(const int4*)(pairs + e0);
        const int4 ub = *(const int4*)(pairs + e0 + 4);
        const int4 va = *(const int4*)(pairs + E + e0);
        const int4 vb = *(const int4*)(pairs + E + e0 + 4);
        const float lab = labels[e0 + l8];               // coalesced, per-lane edge
        const int us[8] = {ua.x, ua.y, ua.z, ua.w, ub.x, ub.y, ub.z, ub.w};
        const int vs[8] = {va.x, va.y, va.z, va.w, vb.x, vb.y, vb.z, vb.w};

        // 32-bit offsets (AB is 12.8 MB): SGPR-base + voffset form, 1 VGPR/addr.
        unsigned int offA[8], offB[8];
#pragma unroll
        for (int k = 0; k < 8; ++k) {
            offA[k] = (unsigned int)us[k] * TWO_D + l8 * 16;
            offB[k] = (unsigned int)vs[k] * TWO_D + D + l8 * 16;
        }

        uintx4 A[8], B[8];
#pragma unroll
        for (int k = 0; k < 8; ++k) {    // 16 loads issued back-to-back, pinned
            asm volatile("global_load_dwordx4 %0, %1, %2"
                         : "=v"(A[k]) : "v"(offA[k]), "s"(AB) : "memory");
            asm volatile("global_load_dwordx4 %0, %1, %2"
                         : "=v"(B[k]) : "v"(offB[k]), "s"(AB) : "memory");
        }

        float z[8];
#define CONS2(k0, k1, cnt)                                                   \
        asm volatile("s_waitcnt vmcnt(" cnt ")" ::: "memory");               \
        __builtin_amdgcn_sched_barrier(0);                                   \
        z[k0] = red8(dot16(A[k0], B[k0], w2a, w2b));                         \
        z[k1] = red8(dot16(A[k1], B[k1], w2a, w2b));
        CONS2(0, 1, "12")
        CONS2(2, 3, "8")
        CONS2(4, 5, "4")
        CONS2(6, 7, "0")
#undef CONS2

        // lane k of the group owns edge k (z is an all-reduce result)
        float zsel = z[0];
#pragma unroll
        for (int k = 1; k < 8; ++k)
            if (l8 == k) zsel = z[k];
        acc = bce(zsel + bb2, lab);
    }

    // wave butterfly -> LDS -> one atomic per block
#pragma unroll
    for (int m = 32; m >= 1; m >>= 1) acc += __shfl_xor(acc, m, 64);
    __shared__ float red[4];
    if ((tid & 63) == 0) red[tid >> 6] = acc;
    __syncthreads();
    if (tid == 0)
        atomicAdd(out, (red[0] + red[1] + red[2] + red[3]) * invE);
}

extern "C" void kernel_launch(void* const* d_in, const int* in_sizes, int n_in,
                              void* d_out, int out_size, void* d_ws, size_t ws_size,
                              hipStream_t stream) {
    const float* x      = (const float*)d_in[0];
    const float* W1     = (const float*)d_in[1];
    const float* b1     = (const float*)d_in[2];
    const float* W2     = (const float*)d_in[3];
    const float* b2     = (const float*)d_in[4];
    const float* labels = (const float*)d_in[5];
    const int*   pairs  = (const int*)d_in[6];

    const int nNodes = in_sizes[0] / D;   // 50000
    const int E      = in_sizes[5];       // 600000

    unsigned char*  AB  = (unsigned char*)d_ws;                       // 12.8 MB fp8
    unsigned short* Wtf = (unsigned short*)((char*)d_ws + 13000704);  // 64 KiB frag-order

    build_wtf<<<16, 256, 0, stream>>>(W1, Wtf);
    gemm_nodes<<<(nNodes + 63) / 64, 256, 0, stream>>>(x, Wtf, b1, AB,
                                                        (float*)d_out, nNodes);
    const int nGroups = (E + 7) / 8;                    // 75000
    const int nBlocks = (nGroups + 31) / 32;            // 2344 (32 groups/block)
    edge_loss<<<nBlocks, 256, 0, stream>>>(AB, pairs, labels, W2, b2,
                                           (float*)d_out, E, 1.0f / (float)E);
}